// Round 1
// baseline (673.627 us; speedup 1.0000x reference)
//
#include <hip/hip_runtime.h>
#include <math.h>

// ---------------- problem dims ----------------
#define B_   32
#define I_   2048
#define J_   16
#define C_   64
#define D_   32
#define CD_  2048           // C_*D_ "columns"
#define W_CSTR (I_*D_*J_)   // 1048576 floats
#define W_ISTR (D_*J_)      // 512 floats
#define X_BSTR (I_*J_)      // 32768 floats
#define EPS_ 1e-7f

typedef _Float16 half2v __attribute__((ext_vector_type(2)));

#if defined(__has_builtin)
# if __has_builtin(__builtin_amdgcn_fdot2)
#  define HAS_FDOT2 1
# endif
#endif

__device__ __forceinline__ float dot2acc(half2v a, half2v b, float c) {
#ifdef HAS_FDOT2
  return __builtin_amdgcn_fdot2(a, b, c, false);
#else
  return c + (float)a[0]*(float)b[0] + (float)a[1]*(float)b[1];
#endif
}

struct alignas(16) H8 { half2v h[4]; };   // 8 f16 = one LDS granule (16 B)

__device__ __forceinline__ half2v pack2(float lo, float hi) {
  half2v r; r[0] = (_Float16)lo; r[1] = (_Float16)hi; return r;
}
__device__ __forceinline__ H8 packH8(float4 a, float4 b) {
  H8 r;
  r.h[0] = pack2(a.x, a.y); r.h[1] = pack2(a.z, a.w);
  r.h[2] = pack2(b.x, b.y); r.h[3] = pack2(b.z, b.w);
  return r;
}

// ================= K1: pass A =================
// part[ic][b][col] = sum_{i in chunk} sum_j x[b,i,j]*W[c,i,d,j], col=c*32+d
// grid (64 ichunks, 4 col-quarters) x 512 threads. All 32 b per block-set,
// so W (268 MB fp32) is streamed exactly once. fp32 FMA (mem-bound anyway).
__global__ __launch_bounds__(512) void k_passA(const float* __restrict__ x,
                                               const float* __restrict__ W,
                                               float* __restrict__ part) {
  __shared__ __align__(16) float xl[B_][J_];       // 2 KB
  const int t     = threadIdx.x;
  const int ic    = blockIdx.x;        // 0..63  (i-chunk of 32)
  const int q4    = blockIdx.y;        // 0..3   (512-col quarter)
  const int bg    = t >> 6;            // 0..7 -> b base bg*4
  const int colid = t & 63;

  float acc[4][8];
  #pragma unroll
  for (int a = 0; a < 4; a++)
    #pragma unroll
    for (int k = 0; k < 8; k++) acc[a][k] = 0.f;

  for (int ii = 0; ii < 32; ii++) {
    const int i = ic*32 + ii;
    __syncthreads();
    if (t < 128) {                      // stage x[:, i, :]
      const int b = t >> 2, q = t & 3;
      *(float4*)(&xl[b][q*4]) = *(const float4*)(x + (size_t)b*X_BSTR + i*J_ + q*4);
    }
    __syncthreads();
    float xv[4][16];
    #pragma unroll
    for (int a = 0; a < 4; a++) {
      #pragma unroll
      for (int q = 0; q < 4; q++) {
        float4 v = *(const float4*)(&xl[bg*4 + a][q*4]);
        xv[a][q*4+0]=v.x; xv[a][q*4+1]=v.y; xv[a][q*4+2]=v.z; xv[a][q*4+3]=v.w;
      }
    }
    #pragma unroll
    for (int k = 0; k < 8; k++) {
      const int col = q4*512 + colid + 64*k;
      const int c = col >> 5, d = col & 31;
      const float* wp = W + (size_t)c*W_CSTR + (size_t)i*W_ISTR + d*J_;
      float4 w0 = *(const float4*)(wp);
      float4 w1 = *(const float4*)(wp+4);
      float4 w2 = *(const float4*)(wp+8);
      float4 w3 = *(const float4*)(wp+12);
      #pragma unroll
      for (int a = 0; a < 4; a++) {
        float s = acc[a][k];
        s += xv[a][0]*w0.x + xv[a][1]*w0.y + xv[a][2]*w0.z + xv[a][3]*w0.w;
        s += xv[a][4]*w1.x + xv[a][5]*w1.y + xv[a][6]*w1.z + xv[a][7]*w1.w;
        s += xv[a][8]*w2.x + xv[a][9]*w2.y + xv[a][10]*w2.z + xv[a][11]*w2.w;
        s += xv[a][12]*w3.x + xv[a][13]*w3.y + xv[a][14]*w3.z + xv[a][15]*w3.w;
        acc[a][k] = s;
      }
    }
  }
  #pragma unroll
  for (int a = 0; a < 4; a++) {
    const int b = bg*4 + a;
    #pragma unroll
    for (int k = 0; k < 8; k++) {
      const int col = q4*512 + colid + 64*k;
      part[(size_t)ic*(B_*CD_) + (size_t)b*CD_ + col] = acc[a][k];
    }
  }
}

// ================= K2a/K5a: chunk reduction =================
__global__ void k_reduce(const float* __restrict__ part, float* __restrict__ sfull) {
  const int g = blockIdx.x*256 + threadIdx.x;     // 0..65535
  float s = 0.f;
  #pragma unroll 8
  for (int ch = 0; ch < 64; ch++) s += part[(size_t)ch*(B_*CD_) + g];
  sfull[g] = s;
}

// ================= K2b/K5b: squash =================
// transposed=1: write v1T[d][b][c]   (for passB1 coalesced v1 reads)
// transposed=0: write out[b][c][d]   (final output)
__global__ void k_squash(const float* __restrict__ sfull, float* __restrict__ outp,
                         float scale, int transposed) {
  const int g = blockIdx.x*256 + threadIdx.x;     // 0..2047 = b*64+c
  if (g >= 2048) return;
  float s[32]; float sn = 0.f;
  #pragma unroll
  for (int d = 0; d < 32; d++) {
    s[d] = sfull[(size_t)g*32 + d] * scale;
    sn += s[d]*s[d];
  }
  const float sc = sn / ((1.f + sn) * sqrtf(sn + EPS_));
  if (transposed) {
    #pragma unroll
    for (int d = 0; d < 32; d++) outp[(size_t)d*2048 + g] = s[d]*sc;
  } else {
    #pragma unroll
    for (int d = 0; d < 32; d++) outp[(size_t)g*32 + d] = s[d]*sc;
  }
}

// ================= K3: pass B1 (b-logits + softmax -> c2) =================
// Per i: stage W[:,i,:,:] as f16 into LDS (64 KB, xor-swizzled granules),
// thread (c = t&63, bg = t>>6) handles b = bg and bg+16.
// b1[b,c] = sum_d v1[b,c,d] * u_hat[b,c,i,d]; softmax over the 64 c's = one wave.
// Register-prefetch of next i's W slab overlaps the HBM stream with compute.
__device__ __forceinline__ void k3_load(const float* __restrict__ W, int i, int t,
                                        float4* buf) {
  #pragma unroll
  for (int k = 0; k < 4; k++) {
    const int g  = t + k*1024;          // granule 0..4095
    const int gc = g >> 6;              // c
    const int gw = g & 63;              // d*2+h
    const float* src = W + (size_t)gc*W_CSTR + (size_t)i*W_ISTR + gw*8;
    buf[2*k]   = *(const float4*)(src);
    buf[2*k+1] = *(const float4*)(src+4);
  }
}
__device__ __forceinline__ void k3_store(int t, const float4* buf, H8* Wl) {
  #pragma unroll
  for (int k = 0; k < 4; k++) {
    const int g  = t + k*1024;
    const int gc = g >> 6;
    const int gw = g & 63;
    Wl[(gc<<6) | (gw ^ (gc & 7))] = packH8(buf[2*k], buf[2*k+1]);
  }
}

__global__ __launch_bounds__(1024) void k_passB1(const float* __restrict__ x,
                                                 const float* __restrict__ W,
                                                 const float* __restrict__ v1T,
                                                 float* __restrict__ c2) {
  __shared__ H8 Wl[4096];               // 64 KB
  const int t  = threadIdx.x;
  const int c  = t & 63;
  const int bg = t >> 6;                // 0..15
  const int cx = c & 7;
  const int i0 = blockIdx.x * 8;

  float4 buf[8];
  k3_load(W, i0, t, buf);
  k3_store(t, buf, Wl);
  __syncthreads();

  for (int ii = 0; ii < 8; ii++) {
    const int i = i0 + ii;
    if (ii < 7) k3_load(W, i+1, t, buf);   // prefetch next slab (regs)

    half2v xh[2][8];
    float  b1[2];
    #pragma unroll
    for (int p = 0; p < 2; p++) {
      const int b = bg + p*16;
      const float4* xp = (const float4*)(x + (size_t)b*X_BSTR + i*J_);
      #pragma unroll
      for (int q = 0; q < 4; q++) {
        float4 v = xp[q];
        xh[p][q*2]   = pack2(v.x, v.y);
        xh[p][q*2+1] = pack2(v.z, v.w);
      }
      b1[p] = 0.f;
    }

    #pragma unroll 4
    for (int d = 0; d < 32; d++) {
      H8 w0 = Wl[(c<<6) | ((2*d)   ^ cx)];
      H8 w1 = Wl[(c<<6) | ((2*d+1) ^ cx)];
      #pragma unroll
      for (int p = 0; p < 2; p++) {
        float u0 = dot2acc(w0.h[0], xh[p][0], 0.f);
        float u1 = dot2acc(w0.h[1], xh[p][1], 0.f);
        u0 = dot2acc(w0.h[2], xh[p][2], u0);
        u1 = dot2acc(w0.h[3], xh[p][3], u1);
        u0 = dot2acc(w1.h[0], xh[p][4], u0);
        u1 = dot2acc(w1.h[1], xh[p][5], u1);
        u0 = dot2acc(w1.h[2], xh[p][6], u0);
        u1 = dot2acc(w1.h[3], xh[p][7], u1);
        const float u  = u0 + u1;
        const float vd = v1T[(size_t)d*2048 + (bg + p*16)*64 + c];
        b1[p] += vd * u;
      }
    }

    // softmax over the 64 capsules (= 64 lanes of this wave), per pair
    #pragma unroll
    for (int p = 0; p < 2; p++) {
      float m = b1[p];
      for (int off = 32; off > 0; off >>= 1) m = fmaxf(m, __shfl_xor(m, off));
      const float e = __expf(b1[p] - m);
      float ss = e;
      for (int off = 32; off > 0; off >>= 1) ss += __shfl_xor(ss, off);
      c2[(size_t)(i*32 + bg + p*16)*64 + c] = e / ss;
    }

    __syncthreads();                    // everyone done reading Wl
    if (ii < 7) k3_store(t, buf, Wl);
    __syncthreads();
  }
}

// ================= K4: pass B2 (s2 partials) =================
// grid (64 ichunks, 4 col-quarters) x 512 threads, thread tile 8b x 4cols.
// W quarter + x + c2 slice staged per i (f16 for W/x). s2 accumulates in regs.
__global__ __launch_bounds__(512, 4) void k_passB2(const float* __restrict__ x,
                                                   const float* __restrict__ W,
                                                   const float* __restrict__ c2,
                                                   float* __restrict__ part) {
  __shared__ H8 Wq[1024];                          // 16 KB
  __shared__ H8 xl[64];                            // 1 KB
  __shared__ __align__(16) float c2l[B_][16];      // 2 KB
  const int t     = threadIdx.x;
  const int ic    = blockIdx.x;        // 0..63
  const int q4    = blockIdx.y;        // 0..3
  const int bg    = t >> 7;            // 0..3 -> b base bg*8
  const int colid = t & 127;

  float s2[8][4];
  #pragma unroll
  for (int a = 0; a < 8; a++)
    #pragma unroll
    for (int k = 0; k < 4; k++) s2[a][k] = 0.f;

  for (int ii = 0; ii < 32; ii++) {
    const int i = ic*32 + ii;
    __syncthreads();
    // stage W quarter (512 cols x 16 j) as f16
    #pragma unroll
    for (int r = 0; r < 2; r++) {
      const int g  = t + r*512;          // 0..1023
      const int cl = g >> 1, h = g & 1;  // col_local, j-half
      const int col = q4*512 + cl;
      const int cc = col >> 5, d = col & 31;
      const float* src = W + (size_t)cc*W_CSTR + (size_t)i*W_ISTR + d*J_ + h*8;
      float4 a = *(const float4*)(src);
      float4 b = *(const float4*)(src+4);
      Wq[g] = packH8(a, b);
    }
    if (t < 64) {                        // stage x as f16
      const int b = t >> 1, h = t & 1;
      const float* src = x + (size_t)b*X_BSTR + i*J_ + h*8;
      float4 a  = *(const float4*)(src);
      float4 bb = *(const float4*)(src+4);
      xl[t] = packH8(a, bb);
    }
    if (t < 128) {                       // stage c2 slice [b][16 c of quarter]
      const int b = t >> 2, qq = t & 3;
      *(float4*)(&c2l[b][qq*4]) =
        *(const float4*)(c2 + (size_t)(i*32 + b)*64 + q4*16 + qq*4);
    }
    __syncthreads();

    float u[8][4];
    #pragma unroll
    for (int a = 0; a < 8; a++)
      #pragma unroll
      for (int k = 0; k < 4; k++) u[a][k] = 0.f;

    #pragma unroll
    for (int h = 0; h < 2; h++) {        // j-halves
      H8 xr[8];
      #pragma unroll
      for (int a = 0; a < 8; a++) xr[a] = xl[(bg*8 + a)*2 + h];
      #pragma unroll
      for (int k = 0; k < 4; k++) {
        H8 wv = Wq[(colid + 128*k)*2 + h];
        #pragma unroll
        for (int a = 0; a < 8; a++) {
          float t0 = dot2acc(wv.h[0], xr[a].h[0], u[a][k]);
          t0 = dot2acc(wv.h[1], xr[a].h[1], t0);
          t0 = dot2acc(wv.h[2], xr[a].h[2], t0);
          u[a][k] = dot2acc(wv.h[3], xr[a].h[3], t0);
        }
      }
    }
    #pragma unroll
    for (int k = 0; k < 4; k++) {
      const int cloc = (colid + 128*k) >> 5;     // 0..15 (c within quarter)
      #pragma unroll
      for (int a = 0; a < 8; a++)
        s2[a][k] += c2l[bg*8 + a][cloc] * u[a][k];
    }
  }

  #pragma unroll
  for (int a = 0; a < 8; a++) {
    const int b = bg*8 + a;
    #pragma unroll
    for (int k = 0; k < 4; k++)
      part[(size_t)ic*(B_*CD_) + (size_t)b*CD_ + q4*512 + colid + 128*k] = s2[a][k];
  }
}

// ================= host =================
extern "C" void kernel_launch(void* const* d_in, const int* in_sizes, int n_in,
                              void* d_out, int out_size, void* d_ws, size_t ws_size,
                              hipStream_t stream) {
  (void)in_sizes; (void)n_in; (void)out_size; (void)ws_size;
  const float* x = (const float*)d_in[0];   // [32, 2048, 16] f32
  const float* W = (const float*)d_in[1];   // [64, 2048, 32, 16] f32
  float* out = (float*)d_out;               // [32, 64, 32] f32

  char* ws = (char*)d_ws;
  float* part  = (float*)(ws);                           // 64*32*2048 f32 = 16 MB
  float* c2    = (float*)(ws + (size_t)16*1024*1024);    // 2048*32*64 f32 = 16 MB
  float* v1T   = (float*)(ws + (size_t)32*1024*1024);    // 32*32*64  f32 = 256 KB
  float* sfull = (float*)(ws + (size_t)32*1024*1024 + 256*1024); // 256 KB
  // total workspace used: ~32.5 MB

  // s0 partials
  k_passA<<<dim3(64, 4), 512, 0, stream>>>(x, W, part);
  // s0, v1 = squash(s0/64) stored transposed [d][b][c]
  k_reduce<<<256, 256, 0, stream>>>(part, sfull);
  k_squash<<<8, 256, 0, stream>>>(sfull, v1T, 1.f/64.f, 1);
  // routing logits + softmax -> c2[i][b][c]
  k_passB1<<<256, 1024, 0, stream>>>(x, W, v1T, c2);
  // s2 partials
  k_passB2<<<dim3(64, 4), 512, 0, stream>>>(x, W, c2, part);
  // s2, v = squash(s2) -> output [b][c][d]
  k_reduce<<<256, 256, 0, stream>>>(part, sfull);
  k_squash<<<8, 256, 0, stream>>>(sfull, out, 1.f, 0);
}